// Round 1
// baseline (677.941 us; speedup 1.0000x reference)
//
#include <hip/hip_runtime.h>
#include <math.h>

// Problem constants (match setup_inputs)
constexpr int N = 20000, D = 256, E = 320000, B = 2, L = 2;

// ---------------- CSR build ----------------
__global__ void count_kernel(const int* __restrict__ src, int* __restrict__ counts, int nE) {
  int e = blockIdx.x * blockDim.x + threadIdx.x;
  if (e < nE) atomicAdd(&counts[src[e]], 1);
}

__global__ __launch_bounds__(1024) void scan_kernel(const int* __restrict__ counts,
                                                    int* __restrict__ rowstart, int n) {
  __shared__ int buf[1024];
  __shared__ int carry;
  int tid = threadIdx.x;
  if (tid == 0) carry = 0;
  __syncthreads();
  for (int base = 0; base < n; base += 1024) {
    int i = base + tid;
    int v = (i < n) ? counts[i] : 0;
    buf[tid] = v;
    __syncthreads();
    for (int off = 1; off < 1024; off <<= 1) {
      int t = (tid >= off) ? buf[tid - off] : 0;
      __syncthreads();
      buf[tid] += t;
      __syncthreads();
    }
    int c = carry;
    if (i < n) rowstart[i] = c + buf[tid] - v;  // exclusive
    __syncthreads();
    if (tid == 1023) carry = c + buf[1023];
    __syncthreads();
  }
  if (tid == 0) rowstart[n] = carry;
}

__global__ void scatter_kernel(const int* __restrict__ src, const int* __restrict__ dst,
                               const int* __restrict__ rowstart, int* __restrict__ fill,
                               int* __restrict__ csr, int nE) {
  int e = blockIdx.x * blockDim.x + threadIdx.x;
  if (e < nE) {
    int s = src[e];
    int p = rowstart[s] + atomicAdd(&fill[s], 1);
    csr[p] = dst[e];
  }
}

// ---------------- wa = W_l @ a_l[:D]  (256-vector) ----------------
__global__ void wa_kernel(const float* __restrict__ W, const float* __restrict__ a,
                          float* __restrict__ wa) {
  int k = threadIdx.x;  // one block of 256
  float s = 0.f;
  for (int d = 0; d < D; ++d) s += W[k * D + d] * a[d];
  wa[k] = s;
}

// ---------------- GEMM: C[M,256] = A[M,256] @ Bm[256,256] ----------------
// 64x64 tile per block, 256 threads, 4x4 register tile per thread.
__global__ __launch_bounds__(256) void gemm_kernel(const float* __restrict__ A,
                                                   const float* __restrict__ Bm,
                                                   float* __restrict__ C, int M) {
  __shared__ __align__(16) float As[16][64];  // As[k][m]
  __shared__ __align__(16) float Bs[16][64];  // Bs[k][n]
  int tid = threadIdx.x;
  int tx = tid & 15, ty = tid >> 4;
  int bm = blockIdx.x * 64, bn = blockIdx.y * 64;
  float acc[4][4] = {};
  for (int k0 = 0; k0 < D; k0 += 16) {
    // stage A (transposed): thread -> row m=tid&63, k-quad kk=(tid>>6)*4
    int m = tid & 63;
    int kk = (tid >> 6) << 2;
    float4 av = make_float4(0.f, 0.f, 0.f, 0.f);
    if (bm + m < M) av = *(const float4*)(A + (size_t)(bm + m) * D + k0 + kk);
    As[kk + 0][m] = av.x;
    As[kk + 1][m] = av.y;
    As[kk + 2][m] = av.z;
    As[kk + 3][m] = av.w;
    // stage B: thread -> k-row kr=tid>>4, n-quad nn=(tid&15)*4
    int kr = tid >> 4;
    int nn = (tid & 15) << 2;
    *(float4*)&Bs[kr][nn] = *(const float4*)(Bm + (size_t)(k0 + kr) * D + bn + nn);
    __syncthreads();
#pragma unroll
    for (int k2 = 0; k2 < 16; ++k2) {
      float4 a4 = *(const float4*)&As[k2][ty << 2];
      float4 b4 = *(const float4*)&Bs[k2][tx << 2];
      float ar[4] = {a4.x, a4.y, a4.z, a4.w};
      float br[4] = {b4.x, b4.y, b4.z, b4.w};
#pragma unroll
      for (int i = 0; i < 4; ++i)
#pragma unroll
        for (int j = 0; j < 4; ++j) acc[i][j] += ar[i] * br[j];
    }
    __syncthreads();
  }
#pragma unroll
  for (int i = 0; i < 4; ++i) {
    int row = bm + (ty << 2) + i;
    if (row < M) {
      float4 o = make_float4(acc[i][0], acc[i][1], acc[i][2], acc[i][3]);
      *(float4*)(C + (size_t)row * D + bn + (tx << 2)) = o;
    }
  }
}

// ---------------- sq[n] = xq[n,:]·wa ; sn[n] = hproj[n,:]·a2 ----------------
__global__ void sqsn_kernel(const float* __restrict__ xq, const float* __restrict__ wa,
                            const float* __restrict__ hproj, const float* __restrict__ a2,
                            float* __restrict__ sq, float* __restrict__ sn, int n) {
  int wave = (blockIdx.x * blockDim.x + threadIdx.x) >> 6;
  int lane = threadIdx.x & 63;
  if (wave >= n) return;
  const float4 xv = *(const float4*)(xq + (size_t)wave * D + (lane << 2));
  const float4 wv = *(const float4*)(wa + (lane << 2));
  const float4 hv = *(const float4*)(hproj + (size_t)wave * D + (lane << 2));
  const float4 avv = *(const float4*)(a2 + (lane << 2));
  float s1 = xv.x * wv.x + xv.y * wv.y + xv.z * wv.z + xv.w * wv.w;
  float s2 = hv.x * avv.x + hv.y * avv.y + hv.z * avv.z + hv.w * avv.w;
  for (int off = 32; off; off >>= 1) {
    s1 += __shfl_down(s1, off);
    s2 += __shfl_down(s2, off);
  }
  if (lane == 0) {
    sq[wave] = s1;
    sn[wave] = s2;
  }
}

// ---------------- aggregation: one wave per node ----------------
__global__ void agg_kernel(const int* __restrict__ rowstart, const int* __restrict__ csr,
                           const float* __restrict__ sq, const float* __restrict__ sn,
                           const float* __restrict__ hproj, const float* __restrict__ resid,
                           float* __restrict__ out, int n) {
  int wave = (blockIdx.x * blockDim.x + threadIdx.x) >> 6;
  int lane = threadIdx.x & 63;
  if (wave >= n) return;
  int beg = rowstart[wave], end = rowstart[wave + 1];
  float sqn = sq[wave];
  float rowsum = 0.f;
  float ax = 0.f, ay = 0.f, az = 0.f, aw = 0.f;
  for (int i = beg; i < end; ++i) {
    int dsti = csr[i];
    float s = sqn + sn[dsti];
    float lrelu = (s >= 0.f) ? s : 0.2f * s;
    float w = expf(-lrelu);
    rowsum += w;
    const float4 hv = *(const float4*)(hproj + (size_t)dsti * D + (lane << 2));
    ax += w * hv.x;
    ay += w * hv.y;
    az += w * hv.z;
    aw += w * hv.w;
  }
  float inv = (rowsum > 0.f) ? 1.f / rowsum : 0.f;
  float4 o = make_float4(ax * inv, ay * inv, az * inv, aw * inv);
  if (resid) {
    const float4 r = *(const float4*)(resid + (size_t)wave * D + (lane << 2));
    o.x += r.x;
    o.y += r.y;
    o.z += r.z;
    o.w += r.w;
  }
  *(float4*)(out + (size_t)wave * D + (lane << 2)) = o;
}

extern "C" void kernel_launch(void* const* d_in, const int* in_sizes, int n_in,
                              void* d_out, int out_size, void* d_ws, size_t ws_size,
                              hipStream_t stream) {
  const float* nodes = (const float*)d_in[0];
  const float* nodesq = (const float*)d_in[1];
  const float* W = (const float*)d_in[2];
  const float* a = (const float*)d_in[3];
  const int* edges = (const int*)d_in[4];
  float* out = (float*)d_out;

  const size_t ND = (size_t)N * D;
  float* ws_f = (float*)d_ws;
  float* hproj = ws_f;            // ND floats
  float* sq = ws_f + ND;          // N
  float* sn = sq + N;             // N
  float* wa = sn + N;             // D
  int* wsi = (int*)(wa + D);
  int* counts = wsi;                          // N (also reused as fill)
  int* rowstart0 = wsi + N;                   // N+1
  int* rowstart1 = rowstart0 + (N + 1);       // N+1
  int* csr0 = rowstart1 + (N + 1);            // E
  int* csr1 = csr0 + E;                       // E
  int* rowstarts[2] = {rowstart0, rowstart1};
  int* csrs[2] = {csr0, csr1};

  // ---- build CSR (by src) once per batch; edges shared across layers ----
  for (int b = 0; b < B; ++b) {
    const int* srcp = edges + (size_t)b * 2 * E;
    const int* dstp = srcp + E;
    hipMemsetAsync(counts, 0, N * sizeof(int), stream);
    count_kernel<<<(E + 255) / 256, 256, 0, stream>>>(srcp, counts, E);
    scan_kernel<<<1, 1024, 0, stream>>>(counts, rowstarts[b], N);
    hipMemsetAsync(counts, 0, N * sizeof(int), stream);
    scatter_kernel<<<(E + 255) / 256, 256, 0, stream>>>(srcp, dstp, rowstarts[b], counts,
                                                        csrs[b], E);
  }

  // ---- layers ----
  dim3 ggrid((N + 63) / 64, D / 64);
  int nwave_blocks = (N * 64 + 255) / 256;
  for (int b = 0; b < B; ++b) {
    const float* nodes_b = nodes + (size_t)b * ND;
    const float* nodesq_b = nodesq + (size_t)b * ND;
    float* hbuf_b = out + (size_t)b * ND;  // layer-0 output staged in d_out slice
    for (int l = 0; l < L; ++l) {
      const float* Wl = W + (size_t)l * D * D;
      const float* al = a + (size_t)l * 2 * D;
      const float* hcur = (l == 0) ? nodes_b : hbuf_b;
      wa_kernel<<<1, 256, 0, stream>>>(Wl, al, wa);
      gemm_kernel<<<ggrid, 256, 0, stream>>>(hcur, Wl, hproj, N);
      sqsn_kernel<<<nwave_blocks, 256, 0, stream>>>(nodesq_b, wa, hproj, al + D, sq, sn, N);
      bool last = (l == L - 1);
      const float* resid = last ? nodes_b : nullptr;
      agg_kernel<<<nwave_blocks, 256, 0, stream>>>(rowstarts[b], csrs[b], sq, sn, hproj,
                                                   resid, hbuf_b, N);
    }
  }
}

// Round 2
// 565.288 us; speedup vs baseline: 1.1993x; 1.1993x over previous
//
#include <hip/hip_runtime.h>
#include <math.h>

constexpr int N = 20000, D = 256, E = 320000, B = 2, L = 2;

typedef __bf16 bf16x8 __attribute__((ext_vector_type(8)));
typedef float f32x4 __attribute__((ext_vector_type(4)));

__device__ __forceinline__ unsigned short f2bf(float f) {
  unsigned int u = __float_as_uint(f);
  u = (u + 0x7FFF + ((u >> 16) & 1)) >> 16;  // RNE
  return (unsigned short)u;
}
__device__ __forceinline__ float bfhi(unsigned int u) {  // high 16 bits as bf16
  return __uint_as_float(u & 0xFFFF0000u);
}
__device__ __forceinline__ float bflo(unsigned int u) {  // low 16 bits as bf16
  return __uint_as_float(u << 16);
}

// ---------------- CSR build ----------------
__global__ void count_kernel(const int* __restrict__ src, int* __restrict__ counts, int nE) {
  int e = blockIdx.x * blockDim.x + threadIdx.x;
  if (e < nE) atomicAdd(&counts[src[e]], 1);
}

__global__ __launch_bounds__(1024) void scan_kernel(const int* __restrict__ counts,
                                                    int* __restrict__ rowstart, int n) {
  __shared__ int buf[1024];
  __shared__ int carry;
  int tid = threadIdx.x;
  if (tid == 0) carry = 0;
  __syncthreads();
  for (int base = 0; base < n; base += 1024) {
    int i = base + tid;
    int v = (i < n) ? counts[i] : 0;
    buf[tid] = v;
    __syncthreads();
    for (int off = 1; off < 1024; off <<= 1) {
      int t = (tid >= off) ? buf[tid - off] : 0;
      __syncthreads();
      buf[tid] += t;
      __syncthreads();
    }
    int c = carry;
    if (i < n) rowstart[i] = c + buf[tid] - v;  // exclusive
    __syncthreads();
    if (tid == 1023) carry = c + buf[1023];
    __syncthreads();
  }
  if (tid == 0) rowstart[n] = carry;
}

__global__ void scatter_kernel(const int* __restrict__ src, const int* __restrict__ dst,
                               const int* __restrict__ rowstart, int* __restrict__ fill,
                               int* __restrict__ csr, int* __restrict__ rowarr, int nE) {
  int e = blockIdx.x * blockDim.x + threadIdx.x;
  if (e < nE) {
    int s = src[e];
    int p = rowstart[s] + atomicAdd(&fill[s], 1);
    csr[p] = dst[e];
    rowarr[p] = s;
  }
}

// ---------------- W transpose + bf16 convert: Wt[l][n][k] = bf16(W[l][k][n]) ----------------
__global__ void wt_kernel(const float* __restrict__ W, unsigned short* __restrict__ Wt) {
  __shared__ float t[16][17];
  int l = blockIdx.z;
  int k = blockIdx.y * 16 + threadIdx.y;
  int n = blockIdx.x * 16 + threadIdx.x;
  t[threadIdx.y][threadIdx.x] = W[l * 65536 + k * 256 + n];
  __syncthreads();
  int nn = blockIdx.x * 16 + threadIdx.y;
  int kk = blockIdx.y * 16 + threadIdx.x;
  Wt[l * 65536 + nn * 256 + kk] = f2bf(t[threadIdx.x][threadIdx.y]);
}

// ---------------- wa[l] = W_l @ a_l[:D] ----------------
__global__ void wa_kernel(const float* __restrict__ W, const float* __restrict__ a,
                          float* __restrict__ wa) {
  int l = blockIdx.x;
  int k = threadIdx.x;
  float s = 0.f;
  for (int d = 0; d < D; ++d) s += W[l * 65536 + k * D + d] * a[l * 2 * D + d];
  wa[l * D + k] = s;
}

// ---------------- sq[l][n] = xq[n,:]·wa[l]  (both layers, one xq pass) ----------------
__global__ void sq_kernel(const float* __restrict__ xq, const float* __restrict__ wa,
                          float* __restrict__ sq, int n) {
  int wave = (blockIdx.x * blockDim.x + threadIdx.x) >> 6;
  int lane = threadIdx.x & 63;
  if (wave >= n) return;
  const float4 xv = *(const float4*)(xq + (size_t)wave * D + (lane << 2));
  const float4 w0 = *(const float4*)(wa + (lane << 2));
  const float4 w1 = *(const float4*)(wa + D + (lane << 2));
  float s0 = xv.x * w0.x + xv.y * w0.y + xv.z * w0.z + xv.w * w0.w;
  float s1 = xv.x * w1.x + xv.y * w1.y + xv.z * w1.z + xv.w * w1.w;
  for (int off = 32; off; off >>= 1) {
    s0 += __shfl_down(s0, off);
    s1 += __shfl_down(s1, off);
  }
  if (lane == 0) {
    sq[wave] = s0;
    sq[n + wave] = s1;
  }
}

// ---------------- MFMA GEMM: Cbf[M,256](bf16) = A[M,256](fp32) @ W; fused sn ----------------
// BM=128, BN=64, BK=32; 256 threads = 4 waves, each wave does 32 rows x 64 cols.
__global__ __launch_bounds__(256) void gemm_mfma(const float* __restrict__ A,
                                                 const unsigned short* __restrict__ Wt,
                                                 unsigned short* __restrict__ Cbf,
                                                 const float* __restrict__ a2,
                                                 float* __restrict__ sn, int M) {
  __shared__ unsigned short As[128 * 32];  // [m][k], 8KB
  __shared__ unsigned short Bs[64 * 32];   // [n][k], 4KB
  int tid = threadIdx.x;
  int bm = blockIdx.x * 128, bn = blockIdx.y * 64;
  int wv = tid >> 6, lane = tid & 63;
  int lm = lane & 15, lq = lane >> 4;
  f32x4 acc[2][4] = {};

  for (int k0 = 0; k0 < 256; k0 += 32) {
    // stage A: thread -> row m=tid>>1, 16-elem half kb=(tid&1)*16
    int m = tid >> 1, kb = (tid & 1) << 4;
    unsigned short tmp[16];
    if (bm + m < M) {
      const float* ap = A + (size_t)(bm + m) * 256 + k0 + kb;
#pragma unroll
      for (int q = 0; q < 4; ++q) {
        float4 v = *(const float4*)(ap + q * 4);
        tmp[q * 4 + 0] = f2bf(v.x);
        tmp[q * 4 + 1] = f2bf(v.y);
        tmp[q * 4 + 2] = f2bf(v.z);
        tmp[q * 4 + 3] = f2bf(v.w);
      }
    } else {
#pragma unroll
      for (int q = 0; q < 16; ++q) tmp[q] = 0;
    }
    ((uint4*)&As[m * 32 + kb])[0] = ((const uint4*)tmp)[0];
    ((uint4*)&As[m * 32 + kb])[1] = ((const uint4*)tmp)[1];
    // stage B: thread -> n=tid>>2, 8-elem chunk kb2=(tid&3)*8
    int n = tid >> 2, kb2 = (tid & 3) << 3;
    *(uint4*)&Bs[n * 32 + kb2] = *(const uint4*)(Wt + (size_t)(bn + n) * 256 + k0 + kb2);
    __syncthreads();

    bf16x8 af0 = *(const bf16x8*)&As[(wv * 32 + lm) * 32 + lq * 8];
    bf16x8 af1 = *(const bf16x8*)&As[(wv * 32 + 16 + lm) * 32 + lq * 8];
#pragma unroll
    for (int nf = 0; nf < 4; ++nf) {
      bf16x8 bfr = *(const bf16x8*)&Bs[(nf * 16 + lm) * 32 + lq * 8];
      acc[0][nf] = __builtin_amdgcn_mfma_f32_16x16x32_bf16(af0, bfr, acc[0][nf], 0, 0, 0);
      acc[1][nf] = __builtin_amdgcn_mfma_f32_16x16x32_bf16(af1, bfr, acc[1][nf], 0, 0, 0);
    }
    __syncthreads();
  }

  // epilogue: D[m][n]: col = bn + nf*16 + lm, row = bm + wv*32 + f*16 + lq*4 + r
  float a2v[4];
#pragma unroll
  for (int nf = 0; nf < 4; ++nf) a2v[nf] = a2[bn + nf * 16 + lm];
#pragma unroll
  for (int f = 0; f < 2; ++f) {
#pragma unroll
    for (int r = 0; r < 4; ++r) {
      int row = bm + wv * 32 + f * 16 + lq * 4 + r;
      if (row < M) {
        float partial = 0.f;
#pragma unroll
        for (int nf = 0; nf < 4; ++nf) {
          float v = acc[f][nf][r];
          Cbf[(size_t)row * 256 + bn + nf * 16 + lm] = f2bf(v);
          partial += v * a2v[nf];
        }
        partial += __shfl_xor(partial, 1);
        partial += __shfl_xor(partial, 2);
        partial += __shfl_xor(partial, 4);
        partial += __shfl_xor(partial, 8);
        if (lm == 0) atomicAdd(&sn[row], partial);
      }
    }
  }
}

// ---------------- edge weights over CSR order ----------------
__global__ void weight_kernel(const int* __restrict__ rowarr, const int* __restrict__ csr,
                              const float* __restrict__ sql, const float* __restrict__ sn,
                              float* __restrict__ w, int nE) {
  int i = blockIdx.x * blockDim.x + threadIdx.x;
  if (i < nE) {
    float s = sql[rowarr[i]] + sn[csr[i]];
    float lrelu = (s >= 0.f) ? s : 0.2f * s;
    w[i] = expf(-lrelu);
  }
}

// ---------------- aggregation: one wave per node, bf16 gathers ----------------
__global__ void agg_kernel(const int* __restrict__ rowstart, const int* __restrict__ csr,
                           const float* __restrict__ wcsr,
                           const unsigned short* __restrict__ hbf,
                           const float* __restrict__ resid, float* __restrict__ out, int n) {
  int wave = (blockIdx.x * blockDim.x + threadIdx.x) >> 6;
  int lane = threadIdx.x & 63;
  if (wave >= n) return;
  int beg = rowstart[wave], end = rowstart[wave + 1];
  float rowsum = 0.f;
  float ax = 0.f, ay = 0.f, az = 0.f, aw = 0.f;
  for (int i = beg; i < end; ++i) {
    int dsti = csr[i];
    float w = wcsr[i];
    uint2 hv = *(const uint2*)(hbf + (size_t)dsti * 256 + (lane << 2));
    rowsum += w;
    ax = fmaf(w, bflo(hv.x), ax);
    ay = fmaf(w, bfhi(hv.x), ay);
    az = fmaf(w, bflo(hv.y), az);
    aw = fmaf(w, bfhi(hv.y), aw);
  }
  float inv = (rowsum > 0.f) ? 1.f / rowsum : 0.f;
  float4 o = make_float4(ax * inv, ay * inv, az * inv, aw * inv);
  if (resid) {
    const float4 r = *(const float4*)(resid + (size_t)wave * D + (lane << 2));
    o.x += r.x;
    o.y += r.y;
    o.z += r.z;
    o.w += r.w;
  }
  *(float4*)(out + (size_t)wave * D + (lane << 2)) = o;
}

extern "C" void kernel_launch(void* const* d_in, const int* in_sizes, int n_in,
                              void* d_out, int out_size, void* d_ws, size_t ws_size,
                              hipStream_t stream) {
  const float* nodes = (const float*)d_in[0];
  const float* nodesq = (const float*)d_in[1];
  const float* W = (const float*)d_in[2];
  const float* a = (const float*)d_in[3];
  const int* edges = (const int*)d_in[4];
  float* out = (float*)d_out;

  const size_t ND = (size_t)N * D;
  // workspace layout
  unsigned short* hbf = (unsigned short*)d_ws;          // N*D bf16
  unsigned short* Wt = hbf + ND;                        // L*D*D bf16
  float* ws_f = (float*)(Wt + (size_t)L * D * D);
  float* sn = ws_f;                  // N
  float* sq = sn + N;                // 2*N
  float* wa = sq + 2 * N;            // 2*D
  float* wcsr = wa + 2 * D;          // E
  int* wsi = (int*)(wcsr + E);
  int* counts = wsi;                           // N
  int* rowstart0 = wsi + N;                    // N+1
  int* rowstart1 = rowstart0 + (N + 1);        // N+1
  int* csr0 = rowstart1 + (N + 1);             // E
  int* csr1 = csr0 + E;                        // E
  int* rowarr0 = csr1 + E;                     // E
  int* rowarr1 = rowarr0 + E;                  // E
  int* rowstarts[2] = {rowstart0, rowstart1};
  int* csrs[2] = {csr0, csr1};
  int* rowarrs[2] = {rowarr0, rowarr1};

  // ---- once: W transpose/convert + wa both layers ----
  wt_kernel<<<dim3(16, 16, 2), dim3(16, 16), 0, stream>>>(W, Wt);
  wa_kernel<<<2, 256, 0, stream>>>(W, a, wa);

  // ---- CSR (by src) once per batch ----
  for (int b = 0; b < B; ++b) {
    const int* srcp = edges + (size_t)b * 2 * E;
    const int* dstp = srcp + E;
    hipMemsetAsync(counts, 0, N * sizeof(int), stream);
    count_kernel<<<(E + 255) / 256, 256, 0, stream>>>(srcp, counts, E);
    scan_kernel<<<1, 1024, 0, stream>>>(counts, rowstarts[b], N);
    hipMemsetAsync(counts, 0, N * sizeof(int), stream);
    scatter_kernel<<<(E + 255) / 256, 256, 0, stream>>>(srcp, dstp, rowstarts[b], counts,
                                                        csrs[b], rowarrs[b], E);
  }

  dim3 ggrid((N + 127) / 128, 4);
  int nwave_blocks = (N * 64 + 255) / 256;
  for (int b = 0; b < B; ++b) {
    const float* nodes_b = nodes + (size_t)b * ND;
    const float* nodesq_b = nodesq + (size_t)b * ND;
    float* hbuf_b = out + (size_t)b * ND;  // layer-0 output staged in d_out slice
    sq_kernel<<<nwave_blocks, 256, 0, stream>>>(nodesq_b, wa, sq, N);
    for (int l = 0; l < L; ++l) {
      const float* al = a + (size_t)l * 2 * D;
      const float* hcur = (l == 0) ? nodes_b : hbuf_b;
      hipMemsetAsync(sn, 0, N * sizeof(float), stream);
      gemm_mfma<<<ggrid, 256, 0, stream>>>(hcur, Wt + (size_t)l * D * D, hbf, al + D, sn, N);
      weight_kernel<<<(E + 255) / 256, 256, 0, stream>>>(rowarrs[b], csrs[b], sq + (size_t)l * N,
                                                         sn, wcsr, E);
      bool last = (l == L - 1);
      const float* resid = last ? nodes_b : nullptr;
      agg_kernel<<<nwave_blocks, 256, 0, stream>>>(rowstarts[b], csrs[b], wcsr, hbf, resid,
                                                   hbuf_b, N);
    }
  }
}

// Round 3
// 443.481 us; speedup vs baseline: 1.5287x; 1.2747x over previous
//
#include <hip/hip_runtime.h>
#include <math.h>

constexpr int N = 20000, D = 256, E = 320000, B = 2, L = 2;

typedef __bf16 bf16x8 __attribute__((ext_vector_type(8)));
typedef float f32x4 __attribute__((ext_vector_type(4)));

__device__ __forceinline__ unsigned short f2bf(float f) {
  unsigned int u = __float_as_uint(f);
  u = (u + 0x7FFF + ((u >> 16) & 1)) >> 16;  // RNE
  return (unsigned short)u;
}
__device__ __forceinline__ float bfhi(unsigned int u) { return __uint_as_float(u & 0xFFFF0000u); }
__device__ __forceinline__ float bflo(unsigned int u) { return __uint_as_float(u << 16); }

// ---------------- CSR build ----------------
__global__ void count_kernel(const int* __restrict__ src, int* __restrict__ counts, int nE) {
  int e = blockIdx.x * blockDim.x + threadIdx.x;
  if (e < nE) atomicAdd(&counts[src[e]], 1);
}

// thread-sequential chunks + single 1024-wide LDS scan (exclusive out)
__global__ __launch_bounds__(1024) void scan_kernel(const int* __restrict__ counts,
                                                    int* __restrict__ rowstart, int n) {
  constexpr int CHUNK = 20;  // 1024*20 >= 20000
  __shared__ int sums[1024];
  int tid = threadIdx.x;
  int base = tid * CHUNK;
  int local[CHUNK];
  int s = 0;
#pragma unroll
  for (int i = 0; i < CHUNK; ++i) {
    int g = base + i;
    int v = (g < n) ? counts[g] : 0;
    local[i] = s;
    s += v;
  }
  sums[tid] = s;
  __syncthreads();
  for (int off = 1; off < 1024; off <<= 1) {
    int t = (tid >= off) ? sums[tid - off] : 0;
    __syncthreads();
    sums[tid] += t;
    __syncthreads();
  }
  int prev = (tid == 0) ? 0 : sums[tid - 1];
#pragma unroll
  for (int i = 0; i < CHUNK; ++i) {
    int g = base + i;
    if (g < n) rowstart[g] = prev + local[i];
  }
  if (tid == 1023) rowstart[n] = sums[1023];
}

__global__ void scatter_kernel(const int* __restrict__ src, const int* __restrict__ dst,
                               const int* __restrict__ rowstart, int* __restrict__ fill,
                               int* __restrict__ csr, int nE) {
  int e = blockIdx.x * blockDim.x + threadIdx.x;
  if (e < nE) {
    int s = src[e];
    int p = rowstart[s] + atomicAdd(&fill[s], 1);
    csr[p] = dst[e];
  }
}

// ---------------- W transpose + bf16 convert: Wt[l][n][k] = bf16(W[l][k][n]) ----------------
__global__ void wt_kernel(const float* __restrict__ W, unsigned short* __restrict__ Wt) {
  __shared__ float t[16][17];
  int l = blockIdx.z;
  int k = blockIdx.y * 16 + threadIdx.y;
  int n = blockIdx.x * 16 + threadIdx.x;
  t[threadIdx.y][threadIdx.x] = W[l * 65536 + k * 256 + n];
  __syncthreads();
  int nn = blockIdx.x * 16 + threadIdx.y;
  int kk = blockIdx.y * 16 + threadIdx.x;
  Wt[l * 65536 + nn * 256 + kk] = f2bf(t[threadIdx.x][threadIdx.y]);
}

// ---------------- wa[l] = W_l @ a_l[:D] ----------------
__global__ void wa_kernel(const float* __restrict__ W, const float* __restrict__ a,
                          float* __restrict__ wa) {
  int l = blockIdx.x;
  int k = threadIdx.x;
  float s = 0.f;
  for (int d = 0; d < D; ++d) s += W[l * 65536 + k * D + d] * a[l * 2 * D + d];
  wa[l * D + k] = s;
}

// ---------------- sq[l][n] = xq[n,:]·wa[l] ----------------
__global__ void sq_kernel(const float* __restrict__ xq, const float* __restrict__ wa,
                          float* __restrict__ sq, int n) {
  int wave = (blockIdx.x * blockDim.x + threadIdx.x) >> 6;
  int lane = threadIdx.x & 63;
  if (wave >= n) return;
  const float4 xv = *(const float4*)(xq + (size_t)wave * D + (lane << 2));
  const float4 w0 = *(const float4*)(wa + (lane << 2));
  const float4 w1 = *(const float4*)(wa + D + (lane << 2));
  float s0 = xv.x * w0.x + xv.y * w0.y + xv.z * w0.z + xv.w * w0.w;
  float s1 = xv.x * w1.x + xv.y * w1.y + xv.z * w1.z + xv.w * w1.w;
  for (int off = 32; off; off >>= 1) {
    s0 += __shfl_down(s0, off);
    s1 += __shfl_down(s1, off);
  }
  if (lane == 0) {
    sq[wave] = s0;
    sq[n + wave] = s1;
  }
}

// ---------------- MFMA GEMM: Cbf[M,256](bf16) = A[M,256](fp32) @ W; fused sn ----------------
__global__ __launch_bounds__(256) void gemm_mfma(const float* __restrict__ A,
                                                 const unsigned short* __restrict__ Wt,
                                                 unsigned short* __restrict__ Cbf,
                                                 const float* __restrict__ a2,
                                                 float* __restrict__ sn, int M) {
  __shared__ unsigned short As[128 * 32];  // [m][k]
  __shared__ unsigned short Bs[64 * 32];   // [n][k]
  int tid = threadIdx.x;
  int bm = blockIdx.x * 128, bn = blockIdx.y * 64;
  int wv = tid >> 6, lane = tid & 63;
  int lm = lane & 15, lq = lane >> 4;
  f32x4 acc[2][4] = {};

  for (int k0 = 0; k0 < 256; k0 += 32) {
    int m = tid >> 1, kb = (tid & 1) << 4;
    unsigned short tmp[16];
    if (bm + m < M) {
      const float* ap = A + (size_t)(bm + m) * 256 + k0 + kb;
#pragma unroll
      for (int q = 0; q < 4; ++q) {
        float4 v = *(const float4*)(ap + q * 4);
        tmp[q * 4 + 0] = f2bf(v.x);
        tmp[q * 4 + 1] = f2bf(v.y);
        tmp[q * 4 + 2] = f2bf(v.z);
        tmp[q * 4 + 3] = f2bf(v.w);
      }
    } else {
#pragma unroll
      for (int q = 0; q < 16; ++q) tmp[q] = 0;
    }
    ((uint4*)&As[m * 32 + kb])[0] = ((const uint4*)tmp)[0];
    ((uint4*)&As[m * 32 + kb])[1] = ((const uint4*)tmp)[1];
    int nn = tid >> 2, kb2 = (tid & 3) << 3;
    *(uint4*)&Bs[nn * 32 + kb2] = *(const uint4*)(Wt + (size_t)(bn + nn) * 256 + k0 + kb2);
    __syncthreads();

    bf16x8 af0 = *(const bf16x8*)&As[(wv * 32 + lm) * 32 + lq * 8];
    bf16x8 af1 = *(const bf16x8*)&As[(wv * 32 + 16 + lm) * 32 + lq * 8];
#pragma unroll
    for (int nf = 0; nf < 4; ++nf) {
      bf16x8 bfr = *(const bf16x8*)&Bs[(nf * 16 + lm) * 32 + lq * 8];
      acc[0][nf] = __builtin_amdgcn_mfma_f32_16x16x32_bf16(af0, bfr, acc[0][nf], 0, 0, 0);
      acc[1][nf] = __builtin_amdgcn_mfma_f32_16x16x32_bf16(af1, bfr, acc[1][nf], 0, 0, 0);
    }
    __syncthreads();
  }

  float a2v[4];
#pragma unroll
  for (int nf = 0; nf < 4; ++nf) a2v[nf] = a2[bn + nf * 16 + lm];
#pragma unroll
  for (int f = 0; f < 2; ++f) {
#pragma unroll
    for (int r = 0; r < 4; ++r) {
      int row = bm + wv * 32 + f * 16 + lq * 4 + r;
      if (row < M) {
        float partial = 0.f;
#pragma unroll
        for (int nf = 0; nf < 4; ++nf) {
          float v = acc[f][nf][r];
          Cbf[(size_t)row * 256 + bn + nf * 16 + lm] = f2bf(v);
          partial += v * a2v[nf];
        }
        partial += __shfl_xor(partial, 1);
        partial += __shfl_xor(partial, 2);
        partial += __shfl_xor(partial, 4);
        partial += __shfl_xor(partial, 8);
        if (lm == 0) atomicAdd(&sn[row], partial);
      }
    }
  }
}

// ---------------- fused weight + aggregation: one wave per node ----------------
// Phase 1 (per 64-edge chunk): lane e loads csr idx + sn gather, computes w_e.
// Phase 2: broadcast (idx,w) via readlane (SGPR base gathers), lane = dim slice.
__global__ void agg_kernel(const int* __restrict__ rowstart, const int* __restrict__ csr,
                           const float* __restrict__ sql, const float* __restrict__ sn,
                           const unsigned short* __restrict__ hbf,
                           const float* __restrict__ resid, float* __restrict__ out, int n) {
  int wave = (blockIdx.x * blockDim.x + threadIdx.x) >> 6;
  int lane = threadIdx.x & 63;
  if (wave >= n) return;
  int beg = rowstart[wave], end = rowstart[wave + 1];
  float sqv = sql[wave];
  float rowsum = 0.f;
  float ax = 0.f, ay = 0.f, az = 0.f, aw = 0.f;
  for (int c0 = beg; c0 < end; c0 += 64) {
    int cnt = min(end - c0, 64);
    int idx = 0;
    float w = 0.f;
    if (lane < cnt) {
      idx = csr[c0 + lane];
      float s = sqv + sn[idx];
      float lr = (s >= 0.f) ? s : 0.2f * s;
      w = __expf(-lr);
    }
#pragma unroll 4
    for (int j = 0; j < cnt; ++j) {
      int dsti = __builtin_amdgcn_readlane(idx, j);
      float wj = __uint_as_float(__builtin_amdgcn_readlane(__float_as_uint(w), j));
      rowsum += wj;
      uint2 hv = *(const uint2*)(hbf + (size_t)dsti * 256 + (lane << 2));
      ax = fmaf(wj, bflo(hv.x), ax);
      ay = fmaf(wj, bfhi(hv.x), ay);
      az = fmaf(wj, bflo(hv.y), az);
      aw = fmaf(wj, bfhi(hv.y), aw);
    }
  }
  float inv = (rowsum > 0.f) ? 1.f / rowsum : 0.f;
  float4 o = make_float4(ax * inv, ay * inv, az * inv, aw * inv);
  if (resid) {
    const float4 r = *(const float4*)(resid + (size_t)wave * D + (lane << 2));
    o.x += r.x;
    o.y += r.y;
    o.z += r.z;
    o.w += r.w;
  }
  *(float4*)(out + (size_t)wave * D + (lane << 2)) = o;
}

extern "C" void kernel_launch(void* const* d_in, const int* in_sizes, int n_in,
                              void* d_out, int out_size, void* d_ws, size_t ws_size,
                              hipStream_t stream) {
  const float* nodes = (const float*)d_in[0];
  const float* nodesq = (const float*)d_in[1];
  const float* W = (const float*)d_in[2];
  const float* a = (const float*)d_in[3];
  const int* edges = (const int*)d_in[4];
  float* out = (float*)d_out;

  const size_t ND = (size_t)N * D;
  unsigned short* hbf = (unsigned short*)d_ws;  // N*D bf16
  unsigned short* Wt = hbf + ND;                // L*D*D bf16
  float* ws_f = (float*)(Wt + (size_t)L * D * D);
  float* sn = ws_f;        // N
  float* sq = sn + N;      // 2*N
  float* wa = sq + 2 * N;  // 2*D
  int* wsi = (int*)(wa + 2 * D);
  int* counts = wsi;                     // N
  int* rowstart0 = wsi + N;              // N+1
  int* rowstart1 = rowstart0 + (N + 1);  // N+1
  int* csr0 = rowstart1 + (N + 1);       // E
  int* csr1 = csr0 + E;                  // E
  int* rowstarts[2] = {rowstart0, rowstart1};
  int* csrs[2] = {csr0, csr1};

  wt_kernel<<<dim3(16, 16, 2), dim3(16, 16), 0, stream>>>(W, Wt);
  wa_kernel<<<2, 256, 0, stream>>>(W, a, wa);

  for (int b = 0; b < B; ++b) {
    const int* srcp = edges + (size_t)b * 2 * E;
    const int* dstp = srcp + E;
    hipMemsetAsync(counts, 0, N * sizeof(int), stream);
    count_kernel<<<(E + 255) / 256, 256, 0, stream>>>(srcp, counts, E);
    scan_kernel<<<1, 1024, 0, stream>>>(counts, rowstarts[b], N);
    hipMemsetAsync(counts, 0, N * sizeof(int), stream);
    scatter_kernel<<<(E + 255) / 256, 256, 0, stream>>>(srcp, dstp, rowstarts[b], counts,
                                                        csrs[b], E);
  }

  dim3 ggrid((N + 127) / 128, 4);
  int nwave_blocks = (N * 64 + 255) / 256;
  for (int b = 0; b < B; ++b) {
    const float* nodes_b = nodes + (size_t)b * ND;
    const float* nodesq_b = nodesq + (size_t)b * ND;
    float* hbuf_b = out + (size_t)b * ND;
    sq_kernel<<<nwave_blocks, 256, 0, stream>>>(nodesq_b, wa, sq, N);
    for (int l = 0; l < L; ++l) {
      const float* al = a + (size_t)l * 2 * D;
      const float* hcur = (l == 0) ? nodes_b : hbuf_b;
      hipMemsetAsync(sn, 0, N * sizeof(float), stream);
      gemm_mfma<<<ggrid, 256, 0, stream>>>(hcur, Wt + (size_t)l * D * D, hbf, al + D, sn, N);
      bool last = (l == L - 1);
      const float* resid = last ? nodes_b : nullptr;
      agg_kernel<<<nwave_blocks, 256, 0, stream>>>(rowstarts[b], csrs[b], sq + (size_t)l * N, sn,
                                                   hbf, resid, hbuf_b, N);
    }
  }
}

// Round 4
// 402.480 us; speedup vs baseline: 1.6844x; 1.1019x over previous
//
#include <hip/hip_runtime.h>
#include <math.h>

constexpr int N = 20000, D = 256, E = 320000, B = 2, L = 2;

typedef __bf16 bf16x8 __attribute__((ext_vector_type(8)));
typedef float f32x4 __attribute__((ext_vector_type(4)));

__device__ __forceinline__ unsigned short f2bf(float f) {
  unsigned int u = __float_as_uint(f);
  u = (u + 0x7FFF + ((u >> 16) & 1)) >> 16;  // RNE
  return (unsigned short)u;
}
__device__ __forceinline__ float bfhi(unsigned int u) { return __uint_as_float(u & 0xFFFF0000u); }
__device__ __forceinline__ float bflo(unsigned int u) { return __uint_as_float(u << 16); }

// ---------------- CSR build (both batches in one series) ----------------
// edges layout: [B][2][E]; src(b) at b*2E, dst(b) at b*2E+E.
// For flat e in [0,2E): b = e>=E, src = edges[b*E+e], dst = edges[(b+1)*E+e].
__global__ void count_kernel(const int* __restrict__ edges, int* __restrict__ counts) {
  int e = blockIdx.x * blockDim.x + threadIdx.x;
  if (e < B * E) {
    int b = (e >= E) ? 1 : 0;
    int s = edges[(size_t)b * E + e];
    atomicAdd(&counts[b * N + s], 1);
  }
}

// one block per batch; thread-sequential chunks + 1024-wide LDS scan
__global__ __launch_bounds__(1024) void scan_kernel(const int* __restrict__ counts,
                                                    int* __restrict__ rowstart) {
  constexpr int CHUNK = 20;  // 1024*20 >= 20000
  __shared__ int sums[1024];
  int b = blockIdx.x;
  const int* c = counts + b * N;
  int* rs = rowstart + b * (N + 1);
  int tid = threadIdx.x;
  int base = tid * CHUNK;
  int local[CHUNK];
  int s = 0;
#pragma unroll
  for (int i = 0; i < CHUNK; ++i) {
    int g = base + i;
    int v = (g < N) ? c[g] : 0;
    local[i] = s;
    s += v;
  }
  sums[tid] = s;
  __syncthreads();
  for (int off = 1; off < 1024; off <<= 1) {
    int t = (tid >= off) ? sums[tid - off] : 0;
    __syncthreads();
    sums[tid] += t;
    __syncthreads();
  }
  int prev = (tid == 0) ? 0 : sums[tid - 1];
#pragma unroll
  for (int i = 0; i < CHUNK; ++i) {
    int g = base + i;
    if (g < N) rs[g] = prev + local[i];
  }
  if (tid == 1023) rs[N] = sums[1023];
}

__global__ void scatter_kernel(const int* __restrict__ edges, const int* __restrict__ rowstart,
                               int* __restrict__ fill, int* __restrict__ csr) {
  int e = blockIdx.x * blockDim.x + threadIdx.x;
  if (e < B * E) {
    int b = (e >= E) ? 1 : 0;
    int s = edges[(size_t)b * E + e];
    int d = edges[(size_t)(b + 1) * E + e];
    int p = rowstart[b * (N + 1) + s] + atomicAdd(&fill[b * N + s], 1);
    csr[(size_t)b * E + p] = d;
  }
}

// ---------------- W transpose + bf16 convert: Wt[l][n][k] = bf16(W[l][k][n]) ----------------
__global__ void wt_kernel(const float* __restrict__ W, unsigned short* __restrict__ Wt) {
  __shared__ float t[16][17];
  int l = blockIdx.z;
  int k = blockIdx.y * 16 + threadIdx.y;
  int n = blockIdx.x * 16 + threadIdx.x;
  t[threadIdx.y][threadIdx.x] = W[l * 65536 + k * 256 + n];
  __syncthreads();
  int nn = blockIdx.x * 16 + threadIdx.y;
  int kk = blockIdx.y * 16 + threadIdx.x;
  Wt[l * 65536 + nn * 256 + kk] = f2bf(t[threadIdx.x][threadIdx.y]);
}

// ---------------- wa[l] = W_l @ a_l[:D] ----------------
__global__ void wa_kernel(const float* __restrict__ W, const float* __restrict__ a,
                          float* __restrict__ wa) {
  int l = blockIdx.x;
  int k = threadIdx.x;
  float s = 0.f;
  for (int d = 0; d < D; ++d) s += W[l * 65536 + k * D + d] * a[l * 2 * D + d];
  wa[l * D + k] = s;
}

// ---------------- sq[(b*2+l)][n] = xq[b][n,:]·wa[l], both batches/layers ----------------
__global__ void sq_kernel(const float* __restrict__ xq, const float* __restrict__ wa,
                          float* __restrict__ sq) {
  int wave = (blockIdx.x * blockDim.x + threadIdx.x) >> 6;
  int lane = threadIdx.x & 63;
  int b = blockIdx.y;
  if (wave >= N) return;
  const float4 xv = *(const float4*)(xq + ((size_t)b * N + wave) * D + (lane << 2));
  const float4 w0 = *(const float4*)(wa + (lane << 2));
  const float4 w1 = *(const float4*)(wa + D + (lane << 2));
  float s0 = xv.x * w0.x + xv.y * w0.y + xv.z * w0.z + xv.w * w0.w;
  float s1 = xv.x * w1.x + xv.y * w1.y + xv.z * w1.z + xv.w * w1.w;
  for (int off = 32; off; off >>= 1) {
    s0 += __shfl_down(s0, off);
    s1 += __shfl_down(s1, off);
  }
  if (lane == 0) {
    sq[(b * 2 + 0) * N + wave] = s0;
    sq[(b * 2 + 1) * N + wave] = s1;
  }
}

// ---------------- MFMA GEMM (both batches, grid.z): Cbf = A @ W, fused sn ----------------
// grid = (4, 157, 2): blockIdx.x = column block (fast -> A strip L2 reuse)
__global__ __launch_bounds__(256) void gemm_mfma(const float* __restrict__ A,
                                                 const unsigned short* __restrict__ Wt,
                                                 unsigned short* __restrict__ Cbf,
                                                 const float* __restrict__ a2,
                                                 float* __restrict__ sn, int M) {
  __shared__ unsigned short As[128 * 32];  // [m][k]
  __shared__ unsigned short Bs[64 * 32];   // [n][k]
  int z = blockIdx.z;
  const float* Az = A + (size_t)z * M * 256;
  unsigned short* Cz = Cbf + (size_t)z * M * 256;
  float* snz = sn + (size_t)z * M;
  int tid = threadIdx.x;
  int bm = blockIdx.y * 128, bn = blockIdx.x * 64;
  int wv = tid >> 6, lane = tid & 63;
  int lm = lane & 15, lq = lane >> 4;
  f32x4 acc[2][4] = {};

  for (int k0 = 0; k0 < 256; k0 += 32) {
    int m = tid >> 1, kb = (tid & 1) << 4;
    unsigned short tmp[16];
    if (bm + m < M) {
      const float* ap = Az + (size_t)(bm + m) * 256 + k0 + kb;
#pragma unroll
      for (int q = 0; q < 4; ++q) {
        float4 v = *(const float4*)(ap + q * 4);
        tmp[q * 4 + 0] = f2bf(v.x);
        tmp[q * 4 + 1] = f2bf(v.y);
        tmp[q * 4 + 2] = f2bf(v.z);
        tmp[q * 4 + 3] = f2bf(v.w);
      }
    } else {
#pragma unroll
      for (int q = 0; q < 16; ++q) tmp[q] = 0;
    }
    ((uint4*)&As[m * 32 + kb])[0] = ((const uint4*)tmp)[0];
    ((uint4*)&As[m * 32 + kb])[1] = ((const uint4*)tmp)[1];
    int nn = tid >> 2, kb2 = (tid & 3) << 3;
    *(uint4*)&Bs[nn * 32 + kb2] = *(const uint4*)(Wt + (size_t)(bn + nn) * 256 + k0 + kb2);
    __syncthreads();

    bf16x8 af0 = *(const bf16x8*)&As[(wv * 32 + lm) * 32 + lq * 8];
    bf16x8 af1 = *(const bf16x8*)&As[(wv * 32 + 16 + lm) * 32 + lq * 8];
#pragma unroll
    for (int nf = 0; nf < 4; ++nf) {
      bf16x8 bfr = *(const bf16x8*)&Bs[(nf * 16 + lm) * 32 + lq * 8];
      acc[0][nf] = __builtin_amdgcn_mfma_f32_16x16x32_bf16(af0, bfr, acc[0][nf], 0, 0, 0);
      acc[1][nf] = __builtin_amdgcn_mfma_f32_16x16x32_bf16(af1, bfr, acc[1][nf], 0, 0, 0);
    }
    __syncthreads();
  }

  float a2v[4];
#pragma unroll
  for (int nf = 0; nf < 4; ++nf) a2v[nf] = a2[bn + nf * 16 + lm];
#pragma unroll
  for (int f = 0; f < 2; ++f) {
#pragma unroll
    for (int r = 0; r < 4; ++r) {
      int row = bm + wv * 32 + f * 16 + lq * 4 + r;
      if (row < M) {
        float partial = 0.f;
#pragma unroll
        for (int nf = 0; nf < 4; ++nf) {
          float v = acc[f][nf][r];
          Cz[(size_t)row * 256 + bn + nf * 16 + lm] = f2bf(v);
          partial += v * a2v[nf];
        }
        partial += __shfl_xor(partial, 1);
        partial += __shfl_xor(partial, 2);
        partial += __shfl_xor(partial, 4);
        partial += __shfl_xor(partial, 8);
        if (lm == 0) atomicAdd(&snz[row], partial);
      }
    }
  }
}

// ---------------- fused weight + aggregation: one BLOCK (4 waves) per node ----------------
// Phase 1: lanes load csr idx + sn gather, compute w (redundant per wave).
// Phase 2: wave wv takes edges j = wv, wv+4, ... -> 16 gathers in flight per node.
// Combine partials via LDS; wave 0 stores.
__global__ __launch_bounds__(256) void agg_kernel(const int* __restrict__ rowstart,
                                                  const int* __restrict__ csr,
                                                  const float* __restrict__ sq_all,
                                                  const float* __restrict__ sn,
                                                  const unsigned short* __restrict__ hbf,
                                                  const float* __restrict__ resid,
                                                  float* __restrict__ out, int l) {
  __shared__ float4 part[4][64];
  __shared__ float prow[4];
  int node = blockIdx.x;
  int b = blockIdx.y;
  int tid = threadIdx.x, wv = tid >> 6, lane = tid & 63;
  const int* rs = rowstart + b * (N + 1);
  const int* cs = csr + (size_t)b * E;
  const float* snb = sn + (size_t)b * N;
  const unsigned short* hb = hbf + (size_t)b * N * 256;
  int beg = rs[node], end = rs[node + 1];
  float sqv = sq_all[((b << 1) + l) * N + node];
  float rowsum = 0.f;
  float ax = 0.f, ay = 0.f, az = 0.f, aw = 0.f;
  for (int c0 = beg; c0 < end; c0 += 64) {
    int cnt = min(end - c0, 64);
    int idx = 0;
    float w = 0.f;
    if (lane < cnt) {
      idx = cs[c0 + lane];
      float s = sqv + snb[idx];
      float lr = (s >= 0.f) ? s : 0.2f * s;
      w = __expf(-lr);
    }
#pragma unroll 4
    for (int j = wv; j < cnt; j += 4) {
      int dsti = __builtin_amdgcn_readlane(idx, j);
      float wj = __uint_as_float(__builtin_amdgcn_readlane(__float_as_uint(w), j));
      rowsum += wj;
      uint2 hv = *(const uint2*)(hb + (size_t)dsti * 256 + (lane << 2));
      ax = fmaf(wj, bflo(hv.x), ax);
      ay = fmaf(wj, bfhi(hv.x), ay);
      az = fmaf(wj, bflo(hv.y), az);
      aw = fmaf(wj, bfhi(hv.y), aw);
    }
  }
  part[wv][lane] = make_float4(ax, ay, az, aw);
  if (lane == 0) prow[wv] = rowsum;
  __syncthreads();
  if (wv == 0) {
    float4 p1 = part[1][lane], p2 = part[2][lane], p3 = part[3][lane];
    float rsum = prow[0] + prow[1] + prow[2] + prow[3];
    float inv = (rsum > 0.f) ? 1.f / rsum : 0.f;
    float4 o;
    o.x = (ax + p1.x + p2.x + p3.x) * inv;
    o.y = (ay + p1.y + p2.y + p3.y) * inv;
    o.z = (az + p1.z + p2.z + p3.z) * inv;
    o.w = (aw + p1.w + p2.w + p3.w) * inv;
    size_t rowoff = ((size_t)b * N + node) * 256 + (lane << 2);
    if (resid) {
      const float4 r = *(const float4*)(resid + rowoff);
      o.x += r.x;
      o.y += r.y;
      o.z += r.z;
      o.w += r.w;
    }
    *(float4*)(out + rowoff) = o;
  }
}

extern "C" void kernel_launch(void* const* d_in, const int* in_sizes, int n_in,
                              void* d_out, int out_size, void* d_ws, size_t ws_size,
                              hipStream_t stream) {
  const float* nodes = (const float*)d_in[0];
  const float* nodesq = (const float*)d_in[1];
  const float* W = (const float*)d_in[2];
  const float* a = (const float*)d_in[3];
  const int* edges = (const int*)d_in[4];
  float* out = (float*)d_out;

  const size_t ND = (size_t)N * D;
  unsigned short* hbf = (unsigned short*)d_ws;  // B*N*D bf16
  unsigned short* Wt = hbf + (size_t)B * ND;    // L*D*D bf16
  float* ws_f = (float*)(Wt + (size_t)L * D * D);
  float* sn = ws_f;          // B*N
  float* sq_all = sn + B * N;  // B*L*N
  float* wa = sq_all + (size_t)B * L * N;  // L*D
  int* wsi = (int*)(wa + L * D);
  int* counts = wsi;                       // B*N
  int* fill = counts + B * N;              // B*N (contiguous -> single memset)
  int* rowstart = fill + B * N;            // B*(N+1)
  int* csr = rowstart + B * (N + 1);       // B*E

  wt_kernel<<<dim3(16, 16, 2), dim3(16, 16), 0, stream>>>(W, Wt);
  wa_kernel<<<2, 256, 0, stream>>>(W, a, wa);

  hipMemsetAsync(counts, 0, (size_t)2 * B * N * sizeof(int), stream);  // counts+fill
  count_kernel<<<(B * E + 255) / 256, 256, 0, stream>>>(edges, counts);
  scan_kernel<<<B, 1024, 0, stream>>>(counts, rowstart);
  scatter_kernel<<<(B * E + 255) / 256, 256, 0, stream>>>(edges, rowstart, fill, csr);

  int nwave_blocks = (N * 64 + 255) / 256;
  sq_kernel<<<dim3(nwave_blocks, B), 256, 0, stream>>>(nodesq, wa, sq_all);

  for (int l = 0; l < L; ++l) {
    const float* al2 = a + (size_t)l * 2 * D + D;
    const float* Acur = (l == 0) ? nodes : out;
    hipMemsetAsync(sn, 0, (size_t)B * N * sizeof(float), stream);
    gemm_mfma<<<dim3(4, (N + 127) / 128, B), 256, 0, stream>>>(Acur, Wt + (size_t)l * D * D,
                                                               hbf, al2, sn, N);
    const float* resid = (l == L - 1) ? nodes : nullptr;
    agg_kernel<<<dim3(N, B), 256, 0, stream>>>(rowstart, csr, sq_all, sn, hbf, resid, out, l);
  }
}

// Round 5
// 391.531 us; speedup vs baseline: 1.7315x; 1.0280x over previous
//
#include <hip/hip_runtime.h>
#include <math.h>

constexpr int N = 20000, D = 256, E = 320000, B = 2, L = 2;

typedef __bf16 bf16x8 __attribute__((ext_vector_type(8)));
typedef float f32x4 __attribute__((ext_vector_type(4)));

__device__ __forceinline__ unsigned short f2bf(float f) {
  unsigned int u = __float_as_uint(f);
  u = (u + 0x7FFF + ((u >> 16) & 1)) >> 16;  // RNE
  return (unsigned short)u;
}
__device__ __forceinline__ float bfhi(unsigned int u) { return __uint_as_float(u & 0xFFFF0000u); }
__device__ __forceinline__ float bflo(unsigned int u) { return __uint_as_float(u << 16); }

// ---------------- fp32 -> bf16 bulk convert (8 elems/thread) ----------------
__global__ void tobf_kernel(const float* __restrict__ in, unsigned short* __restrict__ out,
                            int n8) {
  int i = blockIdx.x * blockDim.x + threadIdx.x;
  if (i < n8) {
    float4 v0 = ((const float4*)in)[i * 2];
    float4 v1 = ((const float4*)in)[i * 2 + 1];
    unsigned short t[8] = {f2bf(v0.x), f2bf(v0.y), f2bf(v0.z), f2bf(v0.w),
                           f2bf(v1.x), f2bf(v1.y), f2bf(v1.z), f2bf(v1.w)};
    ((uint4*)out)[i] = *(uint4*)t;
  }
}

// ---------------- CSR build (both batches) ----------------
__global__ void count_kernel(const int* __restrict__ edges, int* __restrict__ counts) {
  int e = blockIdx.x * blockDim.x + threadIdx.x;
  if (e < B * E) {
    int b = (e >= E) ? 1 : 0;
    int s = edges[(size_t)b * E + e];
    atomicAdd(&counts[b * N + s], 1);
  }
}

__global__ __launch_bounds__(1024) void scan_kernel(const int* __restrict__ counts,
                                                    int* __restrict__ rowstart) {
  constexpr int CHUNK = 20;
  __shared__ int sums[1024];
  int b = blockIdx.x;
  const int* c = counts + b * N;
  int* rs = rowstart + b * (N + 1);
  int tid = threadIdx.x;
  int base = tid * CHUNK;
  int local[CHUNK];
  int s = 0;
#pragma unroll
  for (int i = 0; i < CHUNK; ++i) {
    int g = base + i;
    int v = (g < N) ? c[g] : 0;
    local[i] = s;
    s += v;
  }
  sums[tid] = s;
  __syncthreads();
  for (int off = 1; off < 1024; off <<= 1) {
    int t = (tid >= off) ? sums[tid - off] : 0;
    __syncthreads();
    sums[tid] += t;
    __syncthreads();
  }
  int prev = (tid == 0) ? 0 : sums[tid - 1];
#pragma unroll
  for (int i = 0; i < CHUNK; ++i) {
    int g = base + i;
    if (g < N) rs[g] = prev + local[i];
  }
  if (tid == 1023) rs[N] = sums[1023];
}

__global__ void scatter_kernel(const int* __restrict__ edges, const int* __restrict__ rowstart,
                               int* __restrict__ fill, int* __restrict__ csr) {
  int e = blockIdx.x * blockDim.x + threadIdx.x;
  if (e < B * E) {
    int b = (e >= E) ? 1 : 0;
    int s = edges[(size_t)b * E + e];
    int d = edges[(size_t)(b + 1) * E + e];
    int p = rowstart[b * (N + 1) + s] + atomicAdd(&fill[b * N + s], 1);
    csr[(size_t)b * E + p] = d;
  }
}

// ---------------- W transpose + bf16: Wt[l][n][k] = bf16(W[l][k][n]) ----------------
__global__ void wt_kernel(const float* __restrict__ W, unsigned short* __restrict__ Wt) {
  __shared__ float t[16][17];
  int l = blockIdx.z;
  int k = blockIdx.y * 16 + threadIdx.y;
  int n = blockIdx.x * 16 + threadIdx.x;
  t[threadIdx.y][threadIdx.x] = W[l * 65536 + k * 256 + n];
  __syncthreads();
  int nn = blockIdx.x * 16 + threadIdx.y;
  int kk = blockIdx.y * 16 + threadIdx.x;
  Wt[l * 65536 + nn * 256 + kk] = f2bf(t[threadIdx.x][threadIdx.y]);
}

// ---------------- wa[l] = W_l @ a_l[:D] ----------------
__global__ void wa_kernel(const float* __restrict__ W, const float* __restrict__ a,
                          float* __restrict__ wa) {
  int l = blockIdx.x;
  int k = threadIdx.x;
  float s = 0.f;
  for (int d = 0; d < D; ++d) s += W[l * 65536 + k * D + d] * a[l * 2 * D + d];
  wa[l * D + k] = s;
}

// ---------------- sq[(b*2+l)][n] = xq[b][n,:]·wa[l] ----------------
__global__ void sq_kernel(const float* __restrict__ xq, const float* __restrict__ wa,
                          float* __restrict__ sq) {
  int wave = (blockIdx.x * blockDim.x + threadIdx.x) >> 6;
  int lane = threadIdx.x & 63;
  int b = blockIdx.y;
  if (wave >= N) return;
  const float4 xv = *(const float4*)(xq + ((size_t)b * N + wave) * D + (lane << 2));
  const float4 w0 = *(const float4*)(wa + (lane << 2));
  const float4 w1 = *(const float4*)(wa + D + (lane << 2));
  float s0 = xv.x * w0.x + xv.y * w0.y + xv.z * w0.z + xv.w * w0.w;
  float s1 = xv.x * w1.x + xv.y * w1.y + xv.z * w1.z + xv.w * w1.w;
  for (int off = 32; off; off >>= 1) {
    s0 += __shfl_down(s0, off);
    s1 += __shfl_down(s1, off);
  }
  if (lane == 0) {
    sq[(b * 2 + 0) * N + wave] = s0;
    sq[(b * 2 + 1) * N + wave] = s1;
  }
}

// ---------------- MFMA GEMM (bf16 A, both batches): Cbf = A @ W, fused sn ----------------
__global__ __launch_bounds__(256) void gemm_mfma(const unsigned short* __restrict__ A,
                                                 const unsigned short* __restrict__ Wt,
                                                 unsigned short* __restrict__ Cbf,
                                                 const float* __restrict__ a2,
                                                 float* __restrict__ sn, int M) {
  __shared__ unsigned short As[128 * 32];  // [m][k]
  __shared__ unsigned short Bs[64 * 32];   // [n][k]
  int z = blockIdx.z;
  const unsigned short* Az = A + (size_t)z * M * 256;
  unsigned short* Cz = Cbf + (size_t)z * M * 256;
  float* snz = sn + (size_t)z * M;
  int tid = threadIdx.x;
  int bm = blockIdx.y * 128, bn = blockIdx.x * 64;
  int wv = tid >> 6, lane = tid & 63;
  int lm = lane & 15, lq = lane >> 4;
  f32x4 acc[2][4] = {};

  for (int k0 = 0; k0 < 256; k0 += 32) {
    int m = tid >> 1, kb = (tid & 1) << 4;
    if (bm + m < M) {
      const unsigned short* ap = Az + (size_t)(bm + m) * 256 + k0 + kb;
      *(uint4*)&As[m * 32 + kb] = *(const uint4*)ap;
      *(uint4*)&As[m * 32 + kb + 8] = *(const uint4*)(ap + 8);
    } else {
      uint4 z4 = make_uint4(0, 0, 0, 0);
      *(uint4*)&As[m * 32 + kb] = z4;
      *(uint4*)&As[m * 32 + kb + 8] = z4;
    }
    int nn = tid >> 2, kb2 = (tid & 3) << 3;
    *(uint4*)&Bs[nn * 32 + kb2] = *(const uint4*)(Wt + (size_t)(bn + nn) * 256 + k0 + kb2);
    __syncthreads();

    bf16x8 af0 = *(const bf16x8*)&As[(wv * 32 + lm) * 32 + lq * 8];
    bf16x8 af1 = *(const bf16x8*)&As[(wv * 32 + 16 + lm) * 32 + lq * 8];
#pragma unroll
    for (int nf = 0; nf < 4; ++nf) {
      bf16x8 bfr = *(const bf16x8*)&Bs[(nf * 16 + lm) * 32 + lq * 8];
      acc[0][nf] = __builtin_amdgcn_mfma_f32_16x16x32_bf16(af0, bfr, acc[0][nf], 0, 0, 0);
      acc[1][nf] = __builtin_amdgcn_mfma_f32_16x16x32_bf16(af1, bfr, acc[1][nf], 0, 0, 0);
    }
    __syncthreads();
  }

  float a2v[4];
#pragma unroll
  for (int nf = 0; nf < 4; ++nf) a2v[nf] = a2[bn + nf * 16 + lm];
#pragma unroll
  for (int f = 0; f < 2; ++f) {
#pragma unroll
    for (int r = 0; r < 4; ++r) {
      int row = bm + wv * 32 + f * 16 + lq * 4 + r;
      if (row < M) {
        float partial = 0.f;
#pragma unroll
        for (int nf = 0; nf < 4; ++nf) {
          float v = acc[f][nf][r];
          Cz[(size_t)row * 256 + bn + nf * 16 + lm] = f2bf(v);
          partial += v * a2v[nf];
        }
        partial += __shfl_xor(partial, 1);
        partial += __shfl_xor(partial, 2);
        partial += __shfl_xor(partial, 4);
        partial += __shfl_xor(partial, 8);
        if (lm == 0) atomicAdd(&snz[row], partial);
      }
    }
  }
}

// ---------------- fused weight + aggregation: one block/node, 2 edges per wave ----------------
// Phase 1: lane e loads csr idx + sn gather, computes w; rowsum = wave-reduce(w).
// Phase 2: lane half eg=lane>>5 takes edge j=wv*2+eg (+8 per iter); lane loads uint4
// (16B = 8 bf16 dims). 8 gathers/wave in flight with unroll 4.
__global__ __launch_bounds__(256) void agg_kernel(const int* __restrict__ rowstart,
                                                  const int* __restrict__ csr,
                                                  const float* __restrict__ sq_all,
                                                  const float* __restrict__ sn,
                                                  const unsigned short* __restrict__ hbf,
                                                  const float* __restrict__ resid,
                                                  float* __restrict__ outf,
                                                  unsigned short* __restrict__ outbf, int l) {
  __shared__ float part[4][8][32];
  int node = blockIdx.x, b = blockIdx.y;
  int tid = threadIdx.x, wv = tid >> 6, lane = tid & 63;
  int eg = lane >> 5, dl = lane & 31;
  const int* rs = rowstart + b * (N + 1);
  const int* cs = csr + (size_t)b * E;
  const float* snb = sn + (size_t)b * N;
  const unsigned short* hb = hbf + (size_t)b * N * 256;
  int beg = rs[node], end = rs[node + 1];
  float sqv = sq_all[((b << 1) + l) * N + node];
  float wsum = 0.f;
  float acc[8] = {};
  for (int c0 = beg; c0 < end; c0 += 64) {
    int cnt = min(end - c0, 64);
    int idx = 0;
    float w = 0.f;
    if (lane < cnt) {
      idx = cs[c0 + lane];
      float s = sqv + snb[idx];
      float lr = (s >= 0.f) ? s : 0.2f * s;
      w = __expf(-lr);
    }
    wsum += w;
#pragma unroll 4
    for (int j = wv * 2 + eg; j < cnt; j += 8) {
      int dsti = __shfl(idx, j);
      float wj = __shfl(w, j);
      uint4 hv = *(const uint4*)(hb + (size_t)dsti * 256 + (dl << 3));
      acc[0] = fmaf(wj, bflo(hv.x), acc[0]);
      acc[1] = fmaf(wj, bfhi(hv.x), acc[1]);
      acc[2] = fmaf(wj, bflo(hv.y), acc[2]);
      acc[3] = fmaf(wj, bfhi(hv.y), acc[3]);
      acc[4] = fmaf(wj, bflo(hv.z), acc[4]);
      acc[5] = fmaf(wj, bfhi(hv.z), acc[5]);
      acc[6] = fmaf(wj, bflo(hv.w), acc[6]);
      acc[7] = fmaf(wj, bfhi(hv.w), acc[7]);
    }
  }
  // full-wave rowsum (same value in every wave)
  for (int off = 32; off; off >>= 1) wsum += __shfl_xor(wsum, off);
  // merge lane halves
#pragma unroll
  for (int i = 0; i < 8; ++i) acc[i] += __shfl_xor(acc[i], 32);
  if (eg == 0) {
#pragma unroll
    for (int i = 0; i < 8; ++i) part[wv][i][dl] = acc[i];
  }
  __syncthreads();
  if (wv == 0) {
    float inv = (wsum > 0.f) ? 1.f / wsum : 0.f;
    // lane covers dims lane*4 .. lane*4+3 : part[w][(lane&1)*4+c][lane>>1]
    int r = lane >> 1, c4 = (lane & 1) << 2;
    float4 o;
    o.x = (part[0][c4 + 0][r] + part[1][c4 + 0][r] + part[2][c4 + 0][r] + part[3][c4 + 0][r]) * inv;
    o.y = (part[0][c4 + 1][r] + part[1][c4 + 1][r] + part[2][c4 + 1][r] + part[3][c4 + 1][r]) * inv;
    o.z = (part[0][c4 + 2][r] + part[1][c4 + 2][r] + part[2][c4 + 2][r] + part[3][c4 + 2][r]) * inv;
    o.w = (part[0][c4 + 3][r] + part[1][c4 + 3][r] + part[2][c4 + 3][r] + part[3][c4 + 3][r]) * inv;
    size_t rowoff = ((size_t)b * N + node) * 256 + (lane << 2);
    if (outbf) {
      unsigned short t[4] = {f2bf(o.x), f2bf(o.y), f2bf(o.z), f2bf(o.w)};
      *(uint2*)(outbf + rowoff) = *(uint2*)t;
    } else {
      const float4 rv = *(const float4*)(resid + rowoff);
      o.x += rv.x;
      o.y += rv.y;
      o.z += rv.z;
      o.w += rv.w;
      *(float4*)(outf + rowoff) = o;
    }
  }
}

extern "C" void kernel_launch(void* const* d_in, const int* in_sizes, int n_in,
                              void* d_out, int out_size, void* d_ws, size_t ws_size,
                              hipStream_t stream) {
  const float* nodes = (const float*)d_in[0];
  const float* nodesq = (const float*)d_in[1];
  const float* W = (const float*)d_in[2];
  const float* a = (const float*)d_in[3];
  const int* edges = (const int*)d_in[4];
  float* out = (float*)d_out;

  const size_t ND = (size_t)N * D;
  unsigned short* hbf = (unsigned short*)d_ws;  // B*N*D  (GEMM output h_proj)
  unsigned short* h1bf = hbf + (size_t)B * ND;  // B*N*D  (layer-0 agg output, bf16)
  unsigned short* nbf = h1bf + (size_t)B * ND;  // B*N*D  (nodes in bf16)
  unsigned short* Wt = nbf + (size_t)B * ND;    // L*D*D
  float* ws_f = (float*)(Wt + (size_t)L * D * D);
  float* sn = ws_f;                        // B*N
  float* sq_all = sn + B * N;              // B*L*N
  float* wa = sq_all + (size_t)B * L * N;  // L*D
  int* wsi = (int*)(wa + L * D);
  int* counts = wsi;                  // B*N
  int* fill = counts + B * N;         // B*N
  int* rowstart = fill + B * N;       // B*(N+1)
  int* csr = rowstart + B * (N + 1);  // B*E

  wt_kernel<<<dim3(16, 16, 2), dim3(16, 16), 0, stream>>>(W, Wt);
  wa_kernel<<<2, 256, 0, stream>>>(W, a, wa);
  int n8 = (int)(B * ND / 8);
  tobf_kernel<<<(n8 + 255) / 256, 256, 0, stream>>>(nodes, nbf, n8);

  hipMemsetAsync(counts, 0, (size_t)2 * B * N * sizeof(int), stream);
  count_kernel<<<(B * E + 255) / 256, 256, 0, stream>>>(edges, counts);
  scan_kernel<<<B, 1024, 0, stream>>>(counts, rowstart);
  scatter_kernel<<<(B * E + 255) / 256, 256, 0, stream>>>(edges, rowstart, fill, csr);

  int nwave_blocks = (N * 64 + 255) / 256;
  sq_kernel<<<dim3(nwave_blocks, B), 256, 0, stream>>>(nodesq, wa, sq_all);

  for (int l = 0; l < L; ++l) {
    const float* al2 = a + (size_t)l * 2 * D + D;
    const unsigned short* Acur = (l == 0) ? nbf : h1bf;
    hipMemsetAsync(sn, 0, (size_t)B * N * sizeof(float), stream);
    gemm_mfma<<<dim3(4, (N + 127) / 128, B), 256, 0, stream>>>(Acur, Wt + (size_t)l * D * D,
                                                               hbf, al2, sn, N);
    bool last = (l == L - 1);
    agg_kernel<<<dim3(N, B), 256, 0, stream>>>(rowstart, csr, sq_all, sn, hbf,
                                               last ? nodes : nullptr, last ? out : nullptr,
                                               last ? nullptr : h1bf, l);
  }
}